// Round 1
// baseline (3183.177 us; speedup 1.0000x reference)
//
#include <hip/hip_runtime.h>

#define NUM_USERS 100000
#define NUM_ITEMS 50000
#define N_NODES   150000
#define EMB_DIM   64
#define NNZ       4800000
#define N_LAYERS  3

static constexpr size_t TOTAL = (size_t)N_NODES * EMB_DIM;   // 9,600,000 floats

// init: cur = acc = concat(user_emb, item_emb), vectorized float4
__global__ void lgcn_init(const float4* __restrict__ user_emb,
                          const float4* __restrict__ item_emb,
                          float4* __restrict__ cur,
                          float4* __restrict__ acc) {
    size_t i = (size_t)blockIdx.x * blockDim.x + threadIdx.x;
    const size_t n4 = TOTAL / 4;
    if (i >= n4) return;
    const size_t ub4 = (size_t)NUM_USERS * EMB_DIM / 4;
    float4 v = (i < ub4) ? user_emb[i] : item_emb[i - ub4];
    cur[i] = v;
    acc[i] = v;
}

// scatter SpMM: one wave (64 lanes) per edge; lane d handles dim d.
__global__ void lgcn_spmm_scatter(const int* __restrict__ rows,
                                  const int* __restrict__ cols,
                                  const float* __restrict__ vals,
                                  const float* __restrict__ x,
                                  float* __restrict__ y) {
    size_t t = (size_t)blockIdx.x * blockDim.x + threadIdx.x;
    if (t >= (size_t)NNZ * EMB_DIM) return;
    int e = (int)(t >> 6);
    int d = (int)(t & 63);
    int r = rows[e];
    int c = cols[e];
    float v = vals[e];
    float contrib = v * x[(size_t)c * EMB_DIM + d];
    atomicAdd(&y[(size_t)r * EMB_DIM + d], contrib);
}

// acc = (acc + nxt) * scale, vectorized
__global__ void lgcn_accum(float4* __restrict__ acc,
                           const float4* __restrict__ nxt,
                           float scale) {
    size_t i = (size_t)blockIdx.x * blockDim.x + threadIdx.x;
    const size_t n4 = TOTAL / 4;
    if (i >= n4) return;
    float4 a = acc[i];
    float4 b = nxt[i];
    a.x = (a.x + b.x) * scale;
    a.y = (a.y + b.y) * scale;
    a.z = (a.z + b.z) * scale;
    a.w = (a.w + b.w) * scale;
    acc[i] = a;
}

extern "C" void kernel_launch(void* const* d_in, const int* in_sizes, int n_in,
                              void* d_out, int out_size, void* d_ws, size_t ws_size,
                              hipStream_t stream) {
    const float* user_emb = (const float*)d_in[0];
    const float* item_emb = (const float*)d_in[1];
    const int*   rows     = (const int*)d_in[2];
    const int*   cols     = (const int*)d_in[3];
    const float* vals     = (const float*)d_in[4];
    float* out = (float*)d_out;

    float* cur = (float*)d_ws;
    float* nxt = cur + TOTAL;

    const int BLK = 256;
    const size_t n4 = TOTAL / 4;
    dim3 g_init((n4 + BLK - 1) / BLK);
    lgcn_init<<<g_init, BLK, 0, stream>>>((const float4*)user_emb,
                                          (const float4*)item_emb,
                                          (float4*)cur, (float4*)out);

    const size_t scatter_threads = (size_t)NNZ * EMB_DIM;   // 307.2M
    dim3 g_scat((scatter_threads + BLK - 1) / BLK);

    for (int l = 0; l < N_LAYERS; ++l) {
        hipMemsetAsync(nxt, 0, TOTAL * sizeof(float), stream);
        lgcn_spmm_scatter<<<g_scat, BLK, 0, stream>>>(rows, cols, vals, cur, nxt);
        float scale = (l == N_LAYERS - 1) ? (1.0f / (N_LAYERS + 1)) : 1.0f;
        lgcn_accum<<<g_init, BLK, 0, stream>>>((float4*)out, (const float4*)nxt, scale);
        float* t = cur; cur = nxt; nxt = t;
    }
}

// Round 2
// 1146.074 us; speedup vs baseline: 2.7775x; 2.7775x over previous
//
#include <hip/hip_runtime.h>

#define NUM_USERS 100000
#define NUM_ITEMS 50000
#define N_NODES   150000
#define EMB_DIM   64
#define NNZ       4800000
#define N_LAYERS  3

static constexpr size_t TOTAL = (size_t)N_NODES * EMB_DIM;   // 9,600,000 floats

#define SCAN_BLK 256
#define N_SCAN_BLOCKS ((N_NODES + SCAN_BLK - 1) / SCAN_BLK)  // 586

// ---------------- init: cur = acc = concat(user_emb, item_emb) ----------------
__global__ void lgcn_init(const float4* __restrict__ user_emb,
                          const float4* __restrict__ item_emb,
                          float4* __restrict__ cur,
                          float4* __restrict__ acc) {
    size_t i = (size_t)blockIdx.x * blockDim.x + threadIdx.x;
    const size_t n4 = TOTAL / 4;
    if (i >= n4) return;
    const size_t ub4 = (size_t)NUM_USERS * EMB_DIM / 4;
    float4 v = (i < ub4) ? user_emb[i] : item_emb[i - ub4];
    cur[i] = v;
    acc[i] = v;
}

// ---------------- CSR build ----------------
__global__ void hist_rows(const int* __restrict__ rows, int* __restrict__ counts) {
    int e = blockIdx.x * blockDim.x + threadIdx.x;
    if (e >= NNZ) return;
    atomicAdd(&counts[rows[e]], 1);
}

// Kernel A: per-block sums of counts
__global__ void scan_reduce(const int* __restrict__ counts, int* __restrict__ blockSums) {
    __shared__ int s[SCAN_BLK];
    int i = blockIdx.x * SCAN_BLK + threadIdx.x;
    s[threadIdx.x] = (i < N_NODES) ? counts[i] : 0;
    __syncthreads();
    for (int off = SCAN_BLK / 2; off > 0; off >>= 1) {
        if (threadIdx.x < off) s[threadIdx.x] += s[threadIdx.x + off];
        __syncthreads();
    }
    if (threadIdx.x == 0) blockSums[blockIdx.x] = s[0];
}

// Kernel B: single-block exclusive scan of blockSums (N_SCAN_BLOCKS <= 1024)
__global__ void scan_blocksums(int* __restrict__ blockSums, int* __restrict__ row_ptr) {
    __shared__ int s[1024];
    int t = threadIdx.x;
    int v = (t < N_SCAN_BLOCKS) ? blockSums[t] : 0;
    s[t] = v;
    __syncthreads();
    // Hillis-Steele inclusive scan
    for (int off = 1; off < 1024; off <<= 1) {
        int add = (t >= off) ? s[t - off] : 0;
        __syncthreads();
        s[t] += add;
        __syncthreads();
    }
    if (t < N_SCAN_BLOCKS) blockSums[t] = s[t] - v;   // exclusive
    if (t == 0) row_ptr[N_NODES] = NNZ;
}

// Kernel C: per-block exclusive scan + offset -> row_ptr; also copy to cursor
__global__ void scan_final(const int* __restrict__ counts,
                           const int* __restrict__ blockSums,
                           int* __restrict__ row_ptr,
                           int* __restrict__ cursor) {
    __shared__ int s[SCAN_BLK];
    int i = blockIdx.x * SCAN_BLK + threadIdx.x;
    int t = threadIdx.x;
    int v = (i < N_NODES) ? counts[i] : 0;
    s[t] = v;
    __syncthreads();
    for (int off = 1; off < SCAN_BLK; off <<= 1) {
        int add = (t >= off) ? s[t - off] : 0;
        __syncthreads();
        s[t] += add;
        __syncthreads();
    }
    if (i < N_NODES) {
        int excl = s[t] - v + blockSums[blockIdx.x];
        row_ptr[i] = excl;
        cursor[i]  = excl;
    }
}

// scatter edges into row-sorted order, packing (col, val) into int2
__global__ void edge_scatter(const int* __restrict__ rows,
                             const int* __restrict__ cols,
                             const float* __restrict__ vals,
                             int* __restrict__ cursor,
                             int2* __restrict__ edges) {
    int e = blockIdx.x * blockDim.x + threadIdx.x;
    if (e >= NNZ) return;
    int r = rows[e];
    int pos = atomicAdd(&cursor[r], 1);
    edges[pos] = make_int2(cols[e], __float_as_int(vals[e]));
}

// ---------------- gather SpMM: one wave per row, lane = dim ----------------
// y[r,:] = sum_e val_e * x[col_e,:];  acc[r,:] = (acc[r,:] + y[r,:]) * scale
__global__ void lgcn_spmm_csr(const int* __restrict__ row_ptr,
                              const int2* __restrict__ edges,
                              const float* __restrict__ x,
                              float* __restrict__ y,
                              float* __restrict__ acc,
                              float scale) {
    int wid = blockIdx.x * (blockDim.x >> 6) + (threadIdx.x >> 6);
    if (wid >= N_NODES) return;
    int lane = threadIdx.x & 63;
    int s = row_ptr[wid];
    int epos = row_ptr[wid + 1];
    float a = 0.0f;
    int e = s;
    for (; e + 4 <= epos; e += 4) {
        int2 m0 = edges[e + 0];
        int2 m1 = edges[e + 1];
        int2 m2 = edges[e + 2];
        int2 m3 = edges[e + 3];
        float x0 = x[(size_t)m0.x * EMB_DIM + lane];
        float x1 = x[(size_t)m1.x * EMB_DIM + lane];
        float x2 = x[(size_t)m2.x * EMB_DIM + lane];
        float x3 = x[(size_t)m3.x * EMB_DIM + lane];
        a = fmaf(__int_as_float(m0.y), x0, a);
        a = fmaf(__int_as_float(m1.y), x1, a);
        a = fmaf(__int_as_float(m2.y), x2, a);
        a = fmaf(__int_as_float(m3.y), x3, a);
    }
    for (; e < epos; ++e) {
        int2 m = edges[e];
        a = fmaf(__int_as_float(m.y), x[(size_t)m.x * EMB_DIM + lane], a);
    }
    size_t o = (size_t)wid * EMB_DIM + lane;
    y[o] = a;
    acc[o] = (acc[o] + a) * scale;
}

// ---------------- fallback (round-1 atomic path), used if ws too small ----------------
__global__ void lgcn_spmm_scatter(const int* __restrict__ rows,
                                  const int* __restrict__ cols,
                                  const float* __restrict__ vals,
                                  const float* __restrict__ x,
                                  float* __restrict__ y) {
    size_t t = (size_t)blockIdx.x * blockDim.x + threadIdx.x;
    if (t >= (size_t)NNZ * EMB_DIM) return;
    int e = (int)(t >> 6);
    int d = (int)(t & 63);
    atomicAdd(&y[(size_t)rows[e] * EMB_DIM + d], vals[e] * x[(size_t)cols[e] * EMB_DIM + d]);
}

__global__ void lgcn_accum(float4* __restrict__ acc, const float4* __restrict__ nxt, float scale) {
    size_t i = (size_t)blockIdx.x * blockDim.x + threadIdx.x;
    const size_t n4 = TOTAL / 4;
    if (i >= n4) return;
    float4 a = acc[i]; float4 b = nxt[i];
    a.x = (a.x + b.x) * scale; a.y = (a.y + b.y) * scale;
    a.z = (a.z + b.z) * scale; a.w = (a.w + b.w) * scale;
    acc[i] = a;
}

extern "C" void kernel_launch(void* const* d_in, const int* in_sizes, int n_in,
                              void* d_out, int out_size, void* d_ws, size_t ws_size,
                              hipStream_t stream) {
    const float* user_emb = (const float*)d_in[0];
    const float* item_emb = (const float*)d_in[1];
    const int*   rows     = (const int*)d_in[2];
    const int*   cols     = (const int*)d_in[3];
    const float* vals     = (const float*)d_in[4];
    float* out = (float*)d_out;

    const int BLK = 256;
    const size_t n4 = TOTAL / 4;
    dim3 g_init((n4 + BLK - 1) / BLK);

    // workspace layout
    char* p = (char*)d_ws;
    float* cur = (float*)p;                 p += TOTAL * sizeof(float);      // 38.4 MB
    float* nxt = (float*)p;                 p += TOTAL * sizeof(float);      // 38.4 MB
    int2*  edges = (int2*)p;                p += (size_t)NNZ * sizeof(int2); // 38.4 MB
    int*   counts = (int*)p;                p += (size_t)N_NODES * sizeof(int);
    int*   row_ptr = (int*)p;               p += (size_t)(N_NODES + 1) * sizeof(int);
    int*   cursor = (int*)p;                p += (size_t)N_NODES * sizeof(int);
    int*   blockSums = (int*)p;             p += 1024 * sizeof(int);
    size_t needed = (size_t)(p - (char*)d_ws);

    if (ws_size < needed) {
        // fallback: atomic scatter path (needs only cur+nxt)
        lgcn_init<<<g_init, BLK, 0, stream>>>((const float4*)user_emb, (const float4*)item_emb,
                                              (float4*)cur, (float4*)out);
        const size_t st = (size_t)NNZ * EMB_DIM;
        dim3 g_scat((st + BLK - 1) / BLK);
        for (int l = 0; l < N_LAYERS; ++l) {
            hipMemsetAsync(nxt, 0, TOTAL * sizeof(float), stream);
            lgcn_spmm_scatter<<<g_scat, BLK, 0, stream>>>(rows, cols, vals, cur, nxt);
            float scale = (l == N_LAYERS - 1) ? (1.0f / (N_LAYERS + 1)) : 1.0f;
            lgcn_accum<<<g_init, BLK, 0, stream>>>((float4*)out, (const float4*)nxt, scale);
            float* t = cur; cur = nxt; nxt = t;
        }
        return;
    }

    // ---- CSR build (once per call, reused by all 3 layers) ----
    hipMemsetAsync(counts, 0, (size_t)N_NODES * sizeof(int), stream);
    dim3 g_edges((NNZ + BLK - 1) / BLK);
    hist_rows<<<g_edges, BLK, 0, stream>>>(rows, counts);
    scan_reduce<<<N_SCAN_BLOCKS, SCAN_BLK, 0, stream>>>(counts, blockSums);
    scan_blocksums<<<1, 1024, 0, stream>>>(blockSums, row_ptr);
    scan_final<<<N_SCAN_BLOCKS, SCAN_BLK, 0, stream>>>(counts, blockSums, row_ptr, cursor);
    edge_scatter<<<g_edges, BLK, 0, stream>>>(rows, cols, vals, cursor, edges);

    // ---- init ----
    lgcn_init<<<g_init, BLK, 0, stream>>>((const float4*)user_emb, (const float4*)item_emb,
                                          (float4*)cur, (float4*)out);

    // ---- 3 layers of gather SpMM with fused accumulation ----
    const int WAVES_PER_BLK = BLK / 64;                       // 4 rows per block
    dim3 g_spmm((N_NODES + WAVES_PER_BLK - 1) / WAVES_PER_BLK);
    for (int l = 0; l < N_LAYERS; ++l) {
        float scale = (l == N_LAYERS - 1) ? (1.0f / (N_LAYERS + 1)) : 1.0f;
        lgcn_spmm_csr<<<g_spmm, BLK, 0, stream>>>(row_ptr, edges, cur, nxt, out, scale);
        float* t = cur; cur = nxt; nxt = t;
    }
}